// Round 9
// baseline (243.992 us; speedup 1.0000x reference)
//
#include <hip/hip_runtime.h>
#include <hip/hip_bf16.h>

typedef __hip_bfloat16 bf16;
typedef __attribute__((ext_vector_type(8))) short bf16x8;
typedef __attribute__((ext_vector_type(4))) float f32x4;

// ---------- helpers ----------
__device__ __forceinline__ float bflo(unsigned u) { return __uint_as_float(u << 16); }
__device__ __forceinline__ float bfhi(unsigned u) { return __uint_as_float(u & 0xffff0000u); }
__device__ __forceinline__ bool probe_f32(const void* mask) {
  return *(const unsigned*)mask == 0x3F800000u;
}
__device__ __forceinline__ float ldin(const void* p, size_t i, bool f32) {
  return f32 ? ((const float*)p)[i] : (float)((const bf16*)p)[i];
}

// ---------- 1. prologue: pack_w + prep biases + spike rotation ----------
__global__ __launch_bounds__(256) void prologue(
    const void* w0, const void* w1, const void* w2, const void* w3,
    const void* w4, const void* w5,
    const void* b0, const void* b1, const void* b2, const void* b3,
    const void* b4, const void* b5, const void* g, const void* be,
    const void* q, const void* spike, const void* theta_logit, const void* mask,
    bf16* __restrict__ Wall, float* __restrict__ biasF,
    bf16* __restrict__ q_rot, float* __restrict__ qn) {
  bool f32 = probe_f32(mask);
  int blk = blockIdx.x, t = threadIdx.x;
  if (blk < 1536) {
    const int compT[4][4] = {{0,1,2,3},{1,0,3,2},{2,3,0,1},{3,2,1,0}};
    const float signT[4][4] = {{1.f,-1.f,-1.f,-1.f},{1.f,1.f,-1.f,1.f},{1.f,1.f,1.f,-1.f},{1.f,-1.f,1.f,1.f}};
    int E = blk * 1024 + t * 4;
    int wi = E >> 18;
    const void* src = wi == 0 ? w0 : wi == 1 ? w1 : wi == 2 ? w2 : wi == 3 ? w3 : wi == 4 ? w4 : w5;
    bf16 ov[4];
    #pragma unroll
    for (int j = 0; j < 4; ++j) {
      int e = (E + j) & 262143;
      int o = e >> 9, kk = e & 511;
      int ro = o >> 7, a = o & 127, co = kk >> 7, b2 = kk & 127;
      ov[j] = (bf16)(ldin(src, compT[ro][co] * 16384 + a * 128 + b2, f32) * signT[ro][co]);
    }
    *(uint2*)(Wall + E) = *(const uint2*)ov;
  } else if (blk < 1544) {
    int b = blk - 1536;
    const void* src = b == 0 ? b0 : b == 1 ? b1 : b == 2 ? b2 : b == 3 ? b3
                    : b == 4 ? b4 : b == 5 ? b5 : b == 6 ? g : be;
    biasF[b * 512 + t] = ldin(src, t, f32);
    biasF[b * 512 + 256 + t] = ldin(src, 256 + t, f32);
  } else {
    int row = (blk - 1544) * 2 + (t >> 7);
    int l = t & 127;
    float tl = ldin(theta_logit, 0, f32);
    float tmax = 1.5707963267948966f / (1.0f + __expf(-tl));
    float th = tmax * ldin(spike, row, f32);
    float c = cosf(th), s = sinf(th);
    size_t base = (size_t)row * 512;
    float a = ldin(q, base + l, f32), b = ldin(q, base + 128 + l, f32);
    float cc = ldin(q, base + 256 + l, f32), d = ldin(q, base + 384 + l, f32);
    float r0 = c * a - s * d;
    float r1 = c * b - s * cc;
    float r2 = c * cc + s * b;
    float r3 = c * d + s * a;
    bf16* orow = q_rot + base;
    orow[l] = (bf16)r0; orow[128 + l] = (bf16)r1; orow[256 + l] = (bf16)r2; orow[384 + l] = (bf16)r3;
    qn[(size_t)row * 128 + l] = r0 * r0 + r1 * r1 + r2 * r2 + r3 * r3;
  }
}

// ---------- shared staging: B-tile [64 rows x 512 k] -> fragment-major LDS ----------
__device__ __forceinline__ void stage_B64(const bf16* __restrict__ Bw, int n0, char* Bs, int t) {
  int r = t & 63, cb = (t >> 6) * 16;
  const bf16* src = Bw + (size_t)(n0 + r) * 512;
  #pragma unroll
  for (int i = 0; i < 16; ++i) {
    int c = cb + i;
    int off = (c >> 2) * 4096 + (r >> 4) * 1024 + (((c & 3) * 16 + (r & 15)) * 16);
    *(uint4*)(Bs + off) = *(const uint4*)(src + c * 8);
  }
}

// ---------- 2. GEMM1 (B-stationary, barrier-free K-loop), grid 32x16 ----------
__global__ __launch_bounds__(256, 2) void gemm1(
    const bf16* __restrict__ A, const bf16* __restrict__ Bw,
    const float* __restrict__ bias0, const float* __restrict__ bias1,
    bf16* __restrict__ MQ) {
  __shared__ char Bs[65536];
  const int t = threadIdx.x;
  const int wave = t >> 6, lane = t & 63;
  const int quad = lane >> 4, l16 = lane & 15;
  const int m0 = blockIdx.x * 256, n0 = blockIdx.y * 64;
  stage_B64(Bw, n0, Bs, t);
  __syncthreads();
  const int mbase = m0 + wave * 64;
  f32x4 acc[4][4] = {};
  bf16x8 areg[2][4], breg[2][4];
  #pragma unroll
  for (int mt = 0; mt < 4; ++mt)
    areg[0][mt] = *(const bf16x8*)(A + (size_t)(mbase + mt * 16 + l16) * 512 + quad * 8);
  #pragma unroll
  for (int nt = 0; nt < 4; ++nt)
    breg[0][nt] = *(const bf16x8*)(Bs + nt * 1024 + lane * 16);
  #pragma unroll
  for (int kk = 0; kk < 16; ++kk) {
    const int cur = kk & 1, nxt = cur ^ 1;
    if (kk < 15) {
      const int k2 = (kk + 1) * 32;
      #pragma unroll
      for (int mt = 0; mt < 4; ++mt)
        areg[nxt][mt] = *(const bf16x8*)(A + (size_t)(mbase + mt * 16 + l16) * 512 + k2 + quad * 8);
      #pragma unroll
      for (int nt = 0; nt < 4; ++nt)
        breg[nxt][nt] = *(const bf16x8*)(Bs + (kk + 1) * 4096 + nt * 1024 + lane * 16);
    }
    #pragma unroll
    for (int mt = 0; mt < 4; ++mt)
      #pragma unroll
      for (int nt = 0; nt < 4; ++nt)
        acc[mt][nt] = __builtin_amdgcn_mfma_f32_16x16x32_bf16(areg[cur][mt], breg[cur][nt],
                                                              acc[mt][nt], 0, 0, 0);
  }
  #pragma unroll
  for (int nt = 0; nt < 4; ++nt) {
    int col = n0 + nt * 16 + l16;
    float bv = col < 512 ? bias0[col] : bias1[col - 512];
    #pragma unroll
    for (int mt = 0; mt < 4; ++mt) {
      int rb = mbase + mt * 16 + quad * 4;
      #pragma unroll
      for (int r = 0; r < 4; ++r)
        MQ[(size_t)(rb + r) * 1024 + col] = (bf16)(acc[mt][nt][r] + bv);
    }
  }
}

// ---------- 3. GEMM2: msg_a = attn_o @ Wo^T + b_o, grid 64x8 ----------
__global__ __launch_bounds__(256, 2) void gemm2(
    const bf16* __restrict__ A, const bf16* __restrict__ Bw,
    const float* __restrict__ biasO, bf16* __restrict__ msg_a) {
  __shared__ char Bs[65536];
  const int t = threadIdx.x;
  const int wave = t >> 6, lane = t & 63;
  const int quad = lane >> 4, l16 = lane & 15;
  const int m0 = blockIdx.x * 128, n0 = blockIdx.y * 64;
  stage_B64(Bw, n0, Bs, t);
  __syncthreads();
  const int mbase = m0 + wave * 32;
  f32x4 acc[2][4] = {};
  bf16x8 areg[2][2], breg[2][4];
  #pragma unroll
  for (int mt = 0; mt < 2; ++mt)
    areg[0][mt] = *(const bf16x8*)(A + (size_t)(mbase + mt * 16 + l16) * 512 + quad * 8);
  #pragma unroll
  for (int nt = 0; nt < 4; ++nt)
    breg[0][nt] = *(const bf16x8*)(Bs + nt * 1024 + lane * 16);
  #pragma unroll
  for (int kk = 0; kk < 16; ++kk) {
    const int cur = kk & 1, nxt = cur ^ 1;
    if (kk < 15) {
      const int k2 = (kk + 1) * 32;
      #pragma unroll
      for (int mt = 0; mt < 2; ++mt)
        areg[nxt][mt] = *(const bf16x8*)(A + (size_t)(mbase + mt * 16 + l16) * 512 + k2 + quad * 8);
      #pragma unroll
      for (int nt = 0; nt < 4; ++nt)
        breg[nxt][nt] = *(const bf16x8*)(Bs + (kk + 1) * 4096 + nt * 1024 + lane * 16);
    }
    #pragma unroll
    for (int mt = 0; mt < 2; ++mt)
      #pragma unroll
      for (int nt = 0; nt < 4; ++nt)
        acc[mt][nt] = __builtin_amdgcn_mfma_f32_16x16x32_bf16(areg[cur][mt], breg[cur][nt],
                                                              acc[mt][nt], 0, 0, 0);
  }
  #pragma unroll
  for (int nt = 0; nt < 4; ++nt) {
    int col = n0 + nt * 16 + l16;
    float bv = biasO[col];
    #pragma unroll
    for (int mt = 0; mt < 2; ++mt) {
      int rb = mbase + mt * 16 + quad * 4;
      #pragma unroll
      for (int r = 0; r < 4; ++r)
        msg_a[(size_t)(rb + r) * 512 + col] = (bf16)(acc[mt][nt][r] + bv);
    }
  }
}

// ---------- 4. dist + h fused, OWNED PARTIALS (no memset, no global atomics) ----------
// grid (8 b, 16 nc of 64 rows). h_part[(b*16+k)*16+nc][d], pd_part[(b*16+k)*16+nc].
__global__ __launch_bounds__(256) void dist_h(
    const float* __restrict__ qn, const bf16* __restrict__ q_rot,
    const void* anchors, const void* lsig, const void* mask,
    float* __restrict__ h_part, float* __restrict__ pd_part) {
  bool f32 = probe_f32(mask);
  __shared__ bf16 qr[64 * 512];      // 64 KB
  __shared__ float an[16 * 128];     // 8 KB
  __shared__ float sInc[16 * 64];    // 4 KB
  __shared__ float rs[16];
  __shared__ float pd[16];
  int b = blockIdx.x, nc = blockIdx.y;
  int t = threadIdx.x;
  {
    const uint4* src = (const uint4*)(q_rot + ((size_t)b * 1024 + nc * 64) * 512);
    uint4* dst = (uint4*)qr;
    #pragma unroll
    for (int i = 0; i < 8; ++i) dst[t + i * 256] = src[t + i * 256];
  }
  for (int i = t; i < 2048; i += 256) {
    int k = i >> 7, l = i & 127;
    float a0 = ldin(anchors, k * 512 + l, f32);
    float a1 = ldin(anchors, k * 512 + 128 + l, f32);
    float a2 = ldin(anchors, k * 512 + 256 + l, f32);
    float a3 = ldin(anchors, k * 512 + 384 + l, f32);
    an[i] = a0 * a0 + a1 * a1 + a2 * a2 + a3 * a3;
  }
  if (t < 16) {
    float ls = ldin(lsig, t, f32);
    float ssq = __expf(ls); ssq = fmaxf(ssq * ssq, 1e-6f);
    rs[t] = -1.0f / ssq;
    pd[t] = 0.0f;
  }
  __syncthreads();
  {
    int rl = t >> 2, part = t & 3;
    int n = nc * 64 + rl;
    const float* qrow = qn + ((size_t)b * 1024 + n) * 128 + part * 32;
    f32x4 q4[8];
    #pragma unroll
    for (int i = 0; i < 8; ++i) q4[i] = *(const f32x4*)(qrow + i * 4);
    float sc[16] = {};
    #pragma unroll
    for (int i = 0; i < 8; ++i) {
      #pragma unroll
      for (int k = 0; k < 16; ++k) {
        f32x4 av = *(const f32x4*)(an + k * 128 + part * 32 + i * 4);
        sc[k] += q4[i][0] * av[0] + q4[i][1] * av[1] + q4[i][2] * av[2] + q4[i][3] * av[3];
      }
    }
    #pragma unroll
    for (int k = 0; k < 16; ++k) {
      sc[k] += __shfl_xor(sc[k], 1, 64);
      sc[k] += __shfl_xor(sc[k], 2, 64);
    }
    if (part == 0) {
      float mval = ldin(mask, b * 1024 + n, f32);
      #pragma unroll
      for (int k = 0; k < 16; ++k) {
        float inc = __expf(sc[k] * rs[k]) * mval;
        sInc[k * 64 + rl] = inc;
        atomicAdd(&pd[k], inc);        // LDS atomic
      }
    }
  }
  __syncthreads();
  {
    float acc0[16] = {}, acc1[16] = {};
    for (int nn = 0; nn < 64; ++nn) {
      float v0 = (float)qr[nn * 512 + t];
      float v1 = (float)qr[nn * 512 + 256 + t];
      #pragma unroll
      for (int k = 0; k < 16; ++k) {
        float p = sInc[k * 64 + nn];
        acc0[k] += p * v0;
        acc1[k] += p * v1;
      }
    }
    #pragma unroll
    for (int k = 0; k < 16; ++k) {
      size_t base = ((size_t)(b * 16 + k) * 16 + nc) * 512;
      h_part[base + t] = acc0[k];
      h_part[base + 256 + t] = acc1[k];
    }
  }
  if (t < 16) pd_part[((size_t)(b * 16 + t)) * 16 + nc] = pd[t];
}

// ---------- 5. fused reduce + aggr + K + V: grid 128 x 512 ----------
__global__ __launch_bounds__(512) void qlin_hkv(
    const float* __restrict__ h_part, const float* __restrict__ pd_part,
    const bf16* __restrict__ Wa, const float* __restrict__ ba,
    const bf16* __restrict__ Wk, const float* __restrict__ bk,
    const bf16* __restrict__ Wv, const float* __restrict__ bv,
    float* __restrict__ Kh, float* __restrict__ Vh) {
  __shared__ float xs[512];
  __shared__ float ys[512];
  int row = blockIdx.x;           // 0..127 = b*16+k
  int t = threadIdx.x;            // 512
  float dsum = 0.0f;
  #pragma unroll
  for (int nc = 0; nc < 16; ++nc) dsum += pd_part[row * 16 + nc];
  float dinv = 1.0f / fmaxf(dsum, 1e-6f);
  float hv = 0.0f;
  #pragma unroll
  for (int nc = 0; nc < 16; ++nc) hv += h_part[(size_t)row * 8192 + nc * 512 + t];
  xs[t] = hv * dinv;
  __syncthreads();
  {
    const uint4* wr = (const uint4*)(Wa + (size_t)t * 512);
    float acc = ba[t];
    #pragma unroll 4
    for (int c = 0; c < 64; ++c) {
      uint4 u = wr[c];
      const float* xp = xs + c * 8;
      acc += xp[0] * bflo(u.x) + xp[1] * bfhi(u.x)
           + xp[2] * bflo(u.y) + xp[3] * bfhi(u.y)
           + xp[4] * bflo(u.z) + xp[5] * bfhi(u.z)
           + xp[6] * bflo(u.w) + xp[7] * bfhi(u.w);
    }
    ys[t] = acc;
  }
  __syncthreads();
  {
    const uint4* wk = (const uint4*)(Wk + (size_t)t * 512);
    const uint4* wv = (const uint4*)(Wv + (size_t)t * 512);
    float ak = bk[t], av = bv[t];
    #pragma unroll 2
    for (int c = 0; c < 64; ++c) {
      uint4 uk = wk[c], uv = wv[c];
      const float* xp = ys + c * 8;
      ak += xp[0] * bflo(uk.x) + xp[1] * bfhi(uk.x)
          + xp[2] * bflo(uk.y) + xp[3] * bfhi(uk.y)
          + xp[4] * bflo(uk.z) + xp[5] * bfhi(uk.z)
          + xp[6] * bflo(uk.w) + xp[7] * bfhi(uk.w);
      av += xp[0] * bflo(uv.x) + xp[1] * bfhi(uv.x)
          + xp[2] * bflo(uv.y) + xp[3] * bfhi(uv.y)
          + xp[4] * bflo(uv.z) + xp[5] * bfhi(uv.z)
          + xp[6] * bflo(uv.w) + xp[7] * bfhi(uv.w);
    }
    Kh[(size_t)row * 512 + t] = ak;
    Vh[(size_t)row * 512 + t] = av;
  }
}

// ---------- 6. attention: 16 rows/block, grid 512, full-width phase 1 ----------
__global__ __launch_bounds__(256) void attn_v3(
    const bf16* __restrict__ MQ, const float* __restrict__ Kh_g,
    const float* __restrict__ Vh_g, bf16* __restrict__ attn_o) {
  __shared__ float KV[8 * 1092];
  __shared__ float P[16 * 132];
  const int t = threadIdx.x;         // 256
  const int rowbase = blockIdx.x * 16;
  const int b = rowbase >> 10;
  for (int i = t; i < 8192; i += 256) {
    int k = i >> 9, d = i & 511, h = d >> 6, dd = d & 63;
    KV[h * 1092 + k * 68 + dd] = Kh_g[(size_t)b * 8192 + i];
  }
  __syncthreads();
  {
    const int r = t >> 4, h = (t >> 1) & 7, hf = t & 1;
    const int grow = rowbase + r;
    const uint4* qp = (const uint4*)(MQ + (size_t)grow * 1024 + 512 + h * 64 + hf * 32);
    float q[32];
    #pragma unroll
    for (int i = 0; i < 4; ++i) {
      uint4 u = qp[i];
      q[i * 8 + 0] = bflo(u.x); q[i * 8 + 1] = bfhi(u.x);
      q[i * 8 + 2] = bflo(u.y); q[i * 8 + 3] = bfhi(u.y);
      q[i * 8 + 4] = bflo(u.z); q[i * 8 + 5] = bfhi(u.z);
      q[i * 8 + 6] = bflo(u.w); q[i * 8 + 7] = bfhi(u.w);
    }
    float sc[16];
    #pragma unroll
    for (int k = 0; k < 16; ++k) {
      float s = 0.0f;
      #pragma unroll
      for (int d4 = 0; d4 < 8; ++d4) {
        f32x4 kv = *(const f32x4*)(KV + h * 1092 + k * 68 + hf * 32 + d4 * 4);
        s += q[d4 * 4 + 0] * kv[0] + q[d4 * 4 + 1] * kv[1]
           + q[d4 * 4 + 2] * kv[2] + q[d4 * 4 + 3] * kv[3];
      }
      sc[k] = s;
    }
    #pragma unroll
    for (int k = 0; k < 16; ++k) sc[k] += __shfl_xor(sc[k], 1, 64);
    if (hf == 0) {
      #pragma unroll
      for (int k = 0; k < 16; ++k) sc[k] *= 0.125f;
      float m = sc[0];
      #pragma unroll
      for (int k = 1; k < 16; ++k) m = fmaxf(m, sc[k]);
      float ssum = 0.0f;
      #pragma unroll
      for (int k = 0; k < 16; ++k) { sc[k] = __expf(sc[k] - m); ssum += sc[k]; }
      float inv = 1.0f / ssum;
      #pragma unroll
      for (int k = 0; k < 16; ++k) P[r * 132 + h * 16 + k] = sc[k] * inv;
    }
  }
  __syncthreads();
  for (int i = t; i < 8192; i += 256) {
    int k = i >> 9, d = i & 511, h = d >> 6, dd = d & 63;
    KV[h * 1092 + k * 68 + dd] = Vh_g[(size_t)b * 8192 + i];
  }
  __syncthreads();
  {
    const int r = t >> 4, dg = t & 15;
    #pragma unroll
    for (int h = 0; h < 8; ++h) {
      float a0 = 0, a1 = 0, a2 = 0, a3 = 0;
      #pragma unroll
      for (int k = 0; k < 16; ++k) {
        float p = P[r * 132 + h * 16 + k];
        f32x4 va = *(const f32x4*)(KV + h * 1092 + k * 68 + dg * 4);
        a0 += p * va[0]; a1 += p * va[1]; a2 += p * va[2]; a3 += p * va[3];
      }
      bf16 ov[4] = {(bf16)a0, (bf16)a1, (bf16)a2, (bf16)a3};
      *(uint2*)(attn_o + (size_t)(rowbase + r) * 512 + h * 64 + dg * 4) = *(const uint2*)ov;
    }
  }
}

// ---------- 7. residual + per-component LayerNorm, vectorized, shfl stats ----------
__global__ __launch_bounds__(256) void ln_v2(
    const void* q, const void* mask, const bf16* __restrict__ MQ,
    const bf16* __restrict__ msg_a, const float* __restrict__ gamF, void* out) {
  bool f32 = probe_f32(mask);
  int t = threadIdx.x;
  int row = blockIdx.x * 2 + (t >> 7);
  int l = t & 127;
  int e0 = l * 4;
  float x[4];
  {
    uint2 um = *(const uint2*)(MQ + (size_t)row * 1024 + e0);
    uint2 ua = *(const uint2*)(msg_a + (size_t)row * 512 + e0);
    float qv[4];
    if (f32) {
      f32x4 qq = *(const f32x4*)((const float*)q + (size_t)row * 512 + e0);
      qv[0] = qq[0]; qv[1] = qq[1]; qv[2] = qq[2]; qv[3] = qq[3];
    } else {
      uint2 uq = *(const uint2*)((const bf16*)q + (size_t)row * 512 + e0);
      qv[0] = bflo(uq.x); qv[1] = bfhi(uq.x); qv[2] = bflo(uq.y); qv[3] = bfhi(uq.y);
    }
    x[0] = qv[0] + bflo(um.x) + bflo(ua.x);
    x[1] = qv[1] + bfhi(um.x) + bfhi(ua.x);
    x[2] = qv[2] + bflo(um.y) + bflo(ua.y);
    x[3] = qv[3] + bfhi(um.y) + bfhi(ua.y);
  }
  float s = x[0] + x[1] + x[2] + x[3];
  float s2 = x[0] * x[0] + x[1] * x[1] + x[2] * x[2] + x[3] * x[3];
  #pragma unroll
  for (int off = 1; off <= 16; off <<= 1) {
    s  += __shfl_xor(s, off, 64);
    s2 += __shfl_xor(s2, off, 64);
  }
  float m = s * (1.0f / 128.0f);
  float rinv = rsqrtf(s2 * (1.0f / 128.0f) - m * m + 1e-5f);
  f32x4 ga = *(const f32x4*)(gamF + e0);
  f32x4 be = *(const f32x4*)(gamF + 512 + e0);
  float y[4];
  #pragma unroll
  for (int j = 0; j < 4; ++j) y[j] = (x[j] - m) * rinv * ga[j] + be[j];
  if (f32) {
    f32x4 ov = {y[0], y[1], y[2], y[3]};
    *(f32x4*)((float*)out + (size_t)row * 512 + e0) = ov;
  } else {
    bf16 ov[4] = {(bf16)y[0], (bf16)y[1], (bf16)y[2], (bf16)y[3]};
    *(uint2*)((bf16*)out + (size_t)row * 512 + e0) = *(const uint2*)ov;
  }
}

// ---------- launch ----------
extern "C" void kernel_launch(void* const* d_in, const int* in_sizes, int n_in,
                              void* d_out, int out_size, void* d_ws, size_t ws_size,
                              hipStream_t stream) {
  (void)in_sizes; (void)n_in; (void)out_size; (void)ws_size;
  const void* q      = d_in[0];
  const void* spike  = d_in[1];
  const void* mask   = d_in[2];
  const void* tl     = d_in[3];
  const void* w_prim = d_in[4];
  const void* b_prim = d_in[5];
  const void* anchors= d_in[6];
  const void* lsig   = d_in[7];
  const void* w_aggr = d_in[8];
  const void* b_aggr = d_in[9];
  const void* w_q    = d_in[10];
  const void* b_q    = d_in[11];
  const void* w_k    = d_in[12];
  const void* b_k    = d_in[13];
  const void* w_v    = d_in[14];
  const void* b_v    = d_in[15];
  const void* w_o    = d_in[16];
  const void* b_o    = d_in[17];
  const void* gam    = d_in[18];
  const void* bet    = d_in[19];

  char* ws = (char*)d_ws;
  bf16*  Wall   = (bf16*)(ws + 0);            // 3,145,728
  bf16*  q_rot  = (bf16*)(ws + 3145728);      // 8,388,608
  float* qn     = (float*)(ws + 11534336);    // 4,194,304
  bf16*  MQ     = (bf16*)(ws + 15728640);     // 16,777,216
  float* h_part = (float*)(ws + 32505856);    // 4,194,304
  float* pd_part= (float*)(ws + 36700160);    // 8,192
  float* Kh     = (float*)(ws + 36708352);    // 262,144
  float* Vh     = (float*)(ws + 36970496);    // 262,144
  bf16*  attn_o = (bf16*)(ws + 37232640);     // 8,388,608
  bf16*  msg_a  = (bf16*)(ws + 45621248);     // 8,388,608
  float* biasF  = (float*)(ws + 54009856);    // 16,384 (end 54,026,240)

  prologue<<<5640, 256, 0, stream>>>(w_prim, w_q, w_o, w_aggr, w_k, w_v,
                                     b_prim, b_q, b_o, b_aggr, b_k, b_v, gam, bet,
                                     q, spike, tl, mask, Wall, biasF, q_rot, qn);
  gemm1<<<dim3(32, 16), 256, 0, stream>>>(q_rot, Wall, biasF + 0, biasF + 512, MQ);
  dist_h<<<dim3(8, 16), 256, 0, stream>>>(qn, q_rot, anchors, lsig, mask, h_part, pd_part);
  qlin_hkv<<<128, 512, 0, stream>>>(h_part, pd_part,
                                    Wall + 3 * 262144, biasF + 1536,
                                    Wall + 4 * 262144, biasF + 2048,
                                    Wall + 5 * 262144, biasF + 2560, Kh, Vh);
  attn_v3<<<512, 256, 0, stream>>>(MQ, Kh, Vh, attn_o);
  gemm2<<<dim3(64, 8), 256, 0, stream>>>(attn_o, Wall + 2 * 262144, biasF + 1024, msg_a);
  ln_v2<<<4096, 256, 0, stream>>>(q, mask, MQ, msg_a, biasF + 3072, d_out);
}

// Round 10
// 232.912 us; speedup vs baseline: 1.0476x; 1.0476x over previous
//
#include <hip/hip_runtime.h>
#include <hip/hip_bf16.h>

typedef __hip_bfloat16 bf16;
typedef __attribute__((ext_vector_type(8))) short bf16x8;
typedef __attribute__((ext_vector_type(4))) float f32x4;

// ---------- helpers ----------
__device__ __forceinline__ float bflo(unsigned u) { return __uint_as_float(u << 16); }
__device__ __forceinline__ float bfhi(unsigned u) { return __uint_as_float(u & 0xffff0000u); }
__device__ __forceinline__ bool probe_f32(const void* mask) {
  return *(const unsigned*)mask == 0x3F800000u;
}
__device__ __forceinline__ float ldin(const void* p, size_t i, bool f32) {
  return f32 ? ((const float*)p)[i] : (float)((const bf16*)p)[i];
}

// ---------- 1. prologue: pack_w + prep biases + spike rotation ----------
__global__ __launch_bounds__(256) void prologue(
    const void* w0, const void* w1, const void* w2, const void* w3,
    const void* w4, const void* w5,
    const void* b0, const void* b1, const void* b2, const void* b3,
    const void* b4, const void* b5, const void* g, const void* be,
    const void* q, const void* spike, const void* theta_logit, const void* mask,
    bf16* __restrict__ Wall, float* __restrict__ biasF,
    bf16* __restrict__ q_rot, float* __restrict__ qn) {
  bool f32 = probe_f32(mask);
  int blk = blockIdx.x, t = threadIdx.x;
  if (blk < 1536) {
    const int compT[4][4] = {{0,1,2,3},{1,0,3,2},{2,3,0,1},{3,2,1,0}};
    const float signT[4][4] = {{1.f,-1.f,-1.f,-1.f},{1.f,1.f,-1.f,1.f},{1.f,1.f,1.f,-1.f},{1.f,-1.f,1.f,1.f}};
    int E = blk * 1024 + t * 4;
    int wi = E >> 18;
    const void* src = wi == 0 ? w0 : wi == 1 ? w1 : wi == 2 ? w2 : wi == 3 ? w3 : wi == 4 ? w4 : w5;
    bf16 ov[4];
    #pragma unroll
    for (int j = 0; j < 4; ++j) {
      int e = (E + j) & 262143;
      int o = e >> 9, kk = e & 511;
      int ro = o >> 7, a = o & 127, co = kk >> 7, b2 = kk & 127;
      ov[j] = (bf16)(ldin(src, compT[ro][co] * 16384 + a * 128 + b2, f32) * signT[ro][co]);
    }
    *(uint2*)(Wall + E) = *(const uint2*)ov;
  } else if (blk < 1544) {
    int b = blk - 1536;
    const void* src = b == 0 ? b0 : b == 1 ? b1 : b == 2 ? b2 : b == 3 ? b3
                    : b == 4 ? b4 : b == 5 ? b5 : b == 6 ? g : be;
    biasF[b * 512 + t] = ldin(src, t, f32);
    biasF[b * 512 + 256 + t] = ldin(src, 256 + t, f32);
  } else {
    int row = (blk - 1544) * 2 + (t >> 7);
    int l = t & 127;
    float tl = ldin(theta_logit, 0, f32);
    float tmax = 1.5707963267948966f / (1.0f + __expf(-tl));
    float th = tmax * ldin(spike, row, f32);
    float c = cosf(th), s = sinf(th);
    size_t base = (size_t)row * 512;
    float a = ldin(q, base + l, f32), b = ldin(q, base + 128 + l, f32);
    float cc = ldin(q, base + 256 + l, f32), d = ldin(q, base + 384 + l, f32);
    float r0 = c * a - s * d;
    float r1 = c * b - s * cc;
    float r2 = c * cc + s * b;
    float r3 = c * d + s * a;
    bf16* orow = q_rot + base;
    orow[l] = (bf16)r0; orow[128 + l] = (bf16)r1; orow[256 + l] = (bf16)r2; orow[384 + l] = (bf16)r3;
    qn[(size_t)row * 128 + l] = r0 * r0 + r1 * r1 + r2 * r2 + r3 * r3;
  }
}

// ---------- shared staging: B-tile [64 rows x 512 k] -> fragment-major LDS ----------
__device__ __forceinline__ void stage_B64(const bf16* __restrict__ Bw, int n0, char* Bs, int t) {
  int r = t & 63, cb = (t >> 6) * 16;
  const bf16* src = Bw + (size_t)(n0 + r) * 512;
  #pragma unroll
  for (int i = 0; i < 16; ++i) {
    int c = cb + i;
    int off = (c >> 2) * 4096 + (r >> 4) * 1024 + (((c & 3) * 16 + (r & 15)) * 16);
    *(uint4*)(Bs + off) = *(const uint4*)(src + c * 8);
  }
}

// ---------- 2. FUSED gemm1 + dist_h (independent sections, one launch) ----------
// blocks [0,512): gemm1 tile (m0=(blk>>4)*256, n0=(blk&15)*64)
// blocks [512,640): dist_h (b=(blk-512)>>4, nc=(blk-512)&15)
__global__ __launch_bounds__(256, 2) void gemm_dist(
    const bf16* __restrict__ A, const bf16* __restrict__ Bw,
    const float* __restrict__ bias0, const float* __restrict__ bias1,
    bf16* __restrict__ MQ,
    const float* __restrict__ qn, const void* anchors, const void* lsig,
    const void* mask, float* __restrict__ h_part, float* __restrict__ pd_part) {
  __shared__ char smem[77952];
  const int t = threadIdx.x;
  if (blockIdx.x < 512) {
    char* Bs = smem;
    const int wave = t >> 6, lane = t & 63;
    const int quad = lane >> 4, l16 = lane & 15;
    const int m0 = (blockIdx.x >> 4) * 256, n0 = (blockIdx.x & 15) * 64;
    stage_B64(Bw, n0, Bs, t);
    __syncthreads();
    const int mbase = m0 + wave * 64;
    f32x4 acc[4][4] = {};
    bf16x8 areg[2][4], breg[2][4];
    #pragma unroll
    for (int mt = 0; mt < 4; ++mt)
      areg[0][mt] = *(const bf16x8*)(A + (size_t)(mbase + mt * 16 + l16) * 512 + quad * 8);
    #pragma unroll
    for (int nt = 0; nt < 4; ++nt)
      breg[0][nt] = *(const bf16x8*)(Bs + nt * 1024 + lane * 16);
    #pragma unroll
    for (int kk = 0; kk < 16; ++kk) {
      const int cur = kk & 1, nxt = cur ^ 1;
      if (kk < 15) {
        const int k2 = (kk + 1) * 32;
        #pragma unroll
        for (int mt = 0; mt < 4; ++mt)
          areg[nxt][mt] = *(const bf16x8*)(A + (size_t)(mbase + mt * 16 + l16) * 512 + k2 + quad * 8);
        #pragma unroll
        for (int nt = 0; nt < 4; ++nt)
          breg[nxt][nt] = *(const bf16x8*)(Bs + (kk + 1) * 4096 + nt * 1024 + lane * 16);
      }
      #pragma unroll
      for (int mt = 0; mt < 4; ++mt)
        #pragma unroll
        for (int nt = 0; nt < 4; ++nt)
          acc[mt][nt] = __builtin_amdgcn_mfma_f32_16x16x32_bf16(areg[cur][mt], breg[cur][nt],
                                                                acc[mt][nt], 0, 0, 0);
    }
    #pragma unroll
    for (int nt = 0; nt < 4; ++nt) {
      int col = n0 + nt * 16 + l16;
      float bv = col < 512 ? bias0[col] : bias1[col - 512];
      #pragma unroll
      for (int mt = 0; mt < 4; ++mt) {
        int rb = mbase + mt * 16 + quad * 4;
        #pragma unroll
        for (int r = 0; r < 4; ++r)
          MQ[(size_t)(rb + r) * 1024 + col] = (bf16)(acc[mt][nt][r] + bv);
      }
    }
  } else {
    bool f32 = probe_f32(mask);
    bf16*  qr   = (bf16*)smem;                  // 65536 B
    float* an   = (float*)(smem + 65536);       // 8192 B
    float* sInc = (float*)(smem + 73728);       // 4096 B
    float* rs   = (float*)(smem + 77824);       // 64 B
    float* pd   = (float*)(smem + 77888);       // 64 B
    int bb = blockIdx.x - 512;
    int b = bb >> 4, nc = bb & 15;
    {
      const uint4* src = (const uint4*)((const bf16*)A + ((size_t)b * 1024 + nc * 64) * 512);
      uint4* dst = (uint4*)qr;
      #pragma unroll
      for (int i = 0; i < 8; ++i) dst[t + i * 256] = src[t + i * 256];
    }
    for (int i = t; i < 2048; i += 256) {
      int k = i >> 7, l = i & 127;
      float a0 = ldin(anchors, k * 512 + l, f32);
      float a1 = ldin(anchors, k * 512 + 128 + l, f32);
      float a2 = ldin(anchors, k * 512 + 256 + l, f32);
      float a3 = ldin(anchors, k * 512 + 384 + l, f32);
      an[i] = a0 * a0 + a1 * a1 + a2 * a2 + a3 * a3;
    }
    if (t < 16) {
      float ls = ldin(lsig, t, f32);
      float ssq = __expf(ls); ssq = fmaxf(ssq * ssq, 1e-6f);
      rs[t] = -1.0f / ssq;
      pd[t] = 0.0f;
    }
    __syncthreads();
    {
      int rl = t >> 2, part = t & 3;
      int n = nc * 64 + rl;
      const float* qrow = qn + ((size_t)b * 1024 + n) * 128 + part * 32;
      f32x4 q4[8];
      #pragma unroll
      for (int i = 0; i < 8; ++i) q4[i] = *(const f32x4*)(qrow + i * 4);
      float sc[16] = {};
      #pragma unroll
      for (int i = 0; i < 8; ++i) {
        #pragma unroll
        for (int k = 0; k < 16; ++k) {
          f32x4 av = *(const f32x4*)(an + k * 128 + part * 32 + i * 4);
          sc[k] += q4[i][0] * av[0] + q4[i][1] * av[1] + q4[i][2] * av[2] + q4[i][3] * av[3];
        }
      }
      #pragma unroll
      for (int k = 0; k < 16; ++k) {
        sc[k] += __shfl_xor(sc[k], 1, 64);
        sc[k] += __shfl_xor(sc[k], 2, 64);
      }
      if (part == 0) {
        float mval = ldin(mask, b * 1024 + n, f32);
        #pragma unroll
        for (int k = 0; k < 16; ++k) {
          float inc = __expf(sc[k] * rs[k]) * mval;
          sInc[k * 64 + rl] = inc;
          atomicAdd(&pd[k], inc);
        }
      }
    }
    __syncthreads();
    {
      float acc0[16] = {}, acc1[16] = {};
      for (int nn = 0; nn < 64; ++nn) {
        float v0 = (float)qr[nn * 512 + t];
        float v1 = (float)qr[nn * 512 + 256 + t];
        #pragma unroll
        for (int k = 0; k < 16; ++k) {
          float p = sInc[k * 64 + nn];
          acc0[k] += p * v0;
          acc1[k] += p * v1;
        }
      }
      #pragma unroll
      for (int k = 0; k < 16; ++k) {
        size_t base = ((size_t)(b * 16 + k) * 16 + nc) * 512;
        h_part[base + t] = acc0[k];
        h_part[base + 256 + t] = acc1[k];
      }
    }
    if (t < 16) pd_part[((size_t)(b * 16 + t)) * 16 + nc] = pd[t];
  }
}

// ---------- 3. GEMM2: msg_a = attn_o @ Wo^T + b_o, grid 64x8 ----------
__global__ __launch_bounds__(256, 2) void gemm2(
    const bf16* __restrict__ A, const bf16* __restrict__ Bw,
    const float* __restrict__ biasO, bf16* __restrict__ msg_a) {
  __shared__ char Bs[65536];
  const int t = threadIdx.x;
  const int wave = t >> 6, lane = t & 63;
  const int quad = lane >> 4, l16 = lane & 15;
  const int m0 = blockIdx.x * 128, n0 = blockIdx.y * 64;
  stage_B64(Bw, n0, Bs, t);
  __syncthreads();
  const int mbase = m0 + wave * 32;
  f32x4 acc[2][4] = {};
  bf16x8 areg[2][2], breg[2][4];
  #pragma unroll
  for (int mt = 0; mt < 2; ++mt)
    areg[0][mt] = *(const bf16x8*)(A + (size_t)(mbase + mt * 16 + l16) * 512 + quad * 8);
  #pragma unroll
  for (int nt = 0; nt < 4; ++nt)
    breg[0][nt] = *(const bf16x8*)(Bs + nt * 1024 + lane * 16);
  #pragma unroll
  for (int kk = 0; kk < 16; ++kk) {
    const int cur = kk & 1, nxt = cur ^ 1;
    if (kk < 15) {
      const int k2 = (kk + 1) * 32;
      #pragma unroll
      for (int mt = 0; mt < 2; ++mt)
        areg[nxt][mt] = *(const bf16x8*)(A + (size_t)(mbase + mt * 16 + l16) * 512 + k2 + quad * 8);
      #pragma unroll
      for (int nt = 0; nt < 4; ++nt)
        breg[nxt][nt] = *(const bf16x8*)(Bs + (kk + 1) * 4096 + nt * 1024 + lane * 16);
    }
    #pragma unroll
    for (int mt = 0; mt < 2; ++mt)
      #pragma unroll
      for (int nt = 0; nt < 4; ++nt)
        acc[mt][nt] = __builtin_amdgcn_mfma_f32_16x16x32_bf16(areg[cur][mt], breg[cur][nt],
                                                              acc[mt][nt], 0, 0, 0);
  }
  #pragma unroll
  for (int nt = 0; nt < 4; ++nt) {
    int col = n0 + nt * 16 + l16;
    float bv = biasO[col];
    #pragma unroll
    for (int mt = 0; mt < 2; ++mt) {
      int rb = mbase + mt * 16 + quad * 4;
      #pragma unroll
      for (int r = 0; r < 4; ++r)
        msg_a[(size_t)(rb + r) * 512 + col] = (bf16)(acc[mt][nt][r] + bv);
    }
  }
}

// ---------- 4. fused reduce + aggr(full, redundant) + K/V(half): grid (128,2) x 256 ----------
__global__ __launch_bounds__(256) void qlin_akv(
    const float* __restrict__ h_part, const float* __restrict__ pd_part,
    const bf16* __restrict__ Wa, const float* __restrict__ ba,
    const bf16* __restrict__ Wk, const float* __restrict__ bk,
    const bf16* __restrict__ Wv, const float* __restrict__ bv,
    float* __restrict__ Kh, float* __restrict__ Vh) {
  __shared__ float xs[512];
  __shared__ float ys[512];
  int row = blockIdx.x, half = blockIdx.y;
  int t = threadIdx.x;            // 256
  float dsum = 0.0f;
  #pragma unroll
  for (int nc = 0; nc < 16; ++nc) dsum += pd_part[row * 16 + nc];
  float dinv = 1.0f / fmaxf(dsum, 1e-6f);
  #pragma unroll
  for (int j = 0; j < 2; ++j) {
    int d = j * 256 + t;
    float hv = 0.0f;
    #pragma unroll
    for (int nc = 0; nc < 16; ++nc) hv += h_part[(size_t)row * 8192 + nc * 512 + d];
    xs[d] = hv * dinv;
  }
  __syncthreads();
  // aggr: full row (2 outputs/thread) so the kv phase has everything in LDS
  #pragma unroll
  for (int j = 0; j < 2; ++j) {
    int o = j * 256 + t;
    const uint4* wr = (const uint4*)(Wa + (size_t)o * 512);
    float acc = ba[o];
    #pragma unroll 4
    for (int c = 0; c < 64; ++c) {
      uint4 u = wr[c];
      const float* xp = xs + c * 8;
      acc += xp[0] * bflo(u.x) + xp[1] * bfhi(u.x)
           + xp[2] * bflo(u.y) + xp[3] * bfhi(u.y)
           + xp[4] * bflo(u.z) + xp[5] * bfhi(u.z)
           + xp[6] * bflo(u.w) + xp[7] * bfhi(u.w);
    }
    ys[o] = acc;
  }
  __syncthreads();
  {
    int o = half * 256 + t;
    const uint4* wk = (const uint4*)(Wk + (size_t)o * 512);
    const uint4* wv = (const uint4*)(Wv + (size_t)o * 512);
    float ak = bk[o], av = bv[o];
    #pragma unroll 2
    for (int c = 0; c < 64; ++c) {
      uint4 uk = wk[c], uv = wv[c];
      const float* xp = ys + c * 8;
      ak += xp[0] * bflo(uk.x) + xp[1] * bfhi(uk.x)
          + xp[2] * bflo(uk.y) + xp[3] * bfhi(uk.y)
          + xp[4] * bflo(uk.z) + xp[5] * bfhi(uk.z)
          + xp[6] * bflo(uk.w) + xp[7] * bfhi(uk.w);
      av += xp[0] * bflo(uv.x) + xp[1] * bfhi(uv.x)
          + xp[2] * bflo(uv.y) + xp[3] * bfhi(uv.y)
          + xp[4] * bflo(uv.z) + xp[5] * bfhi(uv.z)
          + xp[6] * bflo(uv.w) + xp[7] * bfhi(uv.w);
    }
    Kh[(size_t)row * 512 + o] = ak;
    Vh[(size_t)row * 512 + o] = av;
  }
}

// ---------- 5. attention: 16 rows/block, grid 512 ----------
__global__ __launch_bounds__(256) void attn_v3(
    const bf16* __restrict__ MQ, const float* __restrict__ Kh_g,
    const float* __restrict__ Vh_g, bf16* __restrict__ attn_o) {
  __shared__ float KV[8 * 1092];
  __shared__ float P[16 * 132];
  const int t = threadIdx.x;         // 256
  const int rowbase = blockIdx.x * 16;
  const int b = rowbase >> 10;
  for (int i = t; i < 8192; i += 256) {
    int k = i >> 9, d = i & 511, h = d >> 6, dd = d & 63;
    KV[h * 1092 + k * 68 + dd] = Kh_g[(size_t)b * 8192 + i];
  }
  __syncthreads();
  {
    const int r = t >> 4, h = (t >> 1) & 7, hf = t & 1;
    const int grow = rowbase + r;
    const uint4* qp = (const uint4*)(MQ + (size_t)grow * 1024 + 512 + h * 64 + hf * 32);
    float q[32];
    #pragma unroll
    for (int i = 0; i < 4; ++i) {
      uint4 u = qp[i];
      q[i * 8 + 0] = bflo(u.x); q[i * 8 + 1] = bfhi(u.x);
      q[i * 8 + 2] = bflo(u.y); q[i * 8 + 3] = bfhi(u.y);
      q[i * 8 + 4] = bflo(u.z); q[i * 8 + 5] = bfhi(u.z);
      q[i * 8 + 6] = bflo(u.w); q[i * 8 + 7] = bfhi(u.w);
    }
    float sc[16];
    #pragma unroll
    for (int k = 0; k < 16; ++k) {
      float s = 0.0f;
      #pragma unroll
      for (int d4 = 0; d4 < 8; ++d4) {
        f32x4 kv = *(const f32x4*)(KV + h * 1092 + k * 68 + hf * 32 + d4 * 4);
        s += q[d4 * 4 + 0] * kv[0] + q[d4 * 4 + 1] * kv[1]
           + q[d4 * 4 + 2] * kv[2] + q[d4 * 4 + 3] * kv[3];
      }
      sc[k] = s;
    }
    #pragma unroll
    for (int k = 0; k < 16; ++k) sc[k] += __shfl_xor(sc[k], 1, 64);
    if (hf == 0) {
      #pragma unroll
      for (int k = 0; k < 16; ++k) sc[k] *= 0.125f;
      float m = sc[0];
      #pragma unroll
      for (int k = 1; k < 16; ++k) m = fmaxf(m, sc[k]);
      float ssum = 0.0f;
      #pragma unroll
      for (int k = 0; k < 16; ++k) { sc[k] = __expf(sc[k] - m); ssum += sc[k]; }
      float inv = 1.0f / ssum;
      #pragma unroll
      for (int k = 0; k < 16; ++k) P[r * 132 + h * 16 + k] = sc[k] * inv;
    }
  }
  __syncthreads();
  for (int i = t; i < 8192; i += 256) {
    int k = i >> 9, d = i & 511, h = d >> 6, dd = d & 63;
    KV[h * 1092 + k * 68 + dd] = Vh_g[(size_t)b * 8192 + i];
  }
  __syncthreads();
  {
    const int r = t >> 4, dg = t & 15;
    #pragma unroll
    for (int h = 0; h < 8; ++h) {
      float a0 = 0, a1 = 0, a2 = 0, a3 = 0;
      #pragma unroll
      for (int k = 0; k < 16; ++k) {
        float p = P[r * 132 + h * 16 + k];
        f32x4 va = *(const f32x4*)(KV + h * 1092 + k * 68 + dg * 4);
        a0 += p * va[0]; a1 += p * va[1]; a2 += p * va[2]; a3 += p * va[3];
      }
      bf16 ov[4] = {(bf16)a0, (bf16)a1, (bf16)a2, (bf16)a3};
      *(uint2*)(attn_o + (size_t)(rowbase + r) * 512 + h * 64 + dg * 4) = *(const uint2*)ov;
    }
  }
}

// ---------- 6. residual + per-component LayerNorm ----------
__global__ __launch_bounds__(256) void ln_v2(
    const void* q, const void* mask, const bf16* __restrict__ MQ,
    const bf16* __restrict__ msg_a, const float* __restrict__ gamF, void* out) {
  bool f32 = probe_f32(mask);
  int t = threadIdx.x;
  int row = blockIdx.x * 2 + (t >> 7);
  int l = t & 127;
  int e0 = l * 4;
  float x[4];
  {
    uint2 um = *(const uint2*)(MQ + (size_t)row * 1024 + e0);
    uint2 ua = *(const uint2*)(msg_a + (size_t)row * 512 + e0);
    float qv[4];
    if (f32) {
      f32x4 qq = *(const f32x4*)((const float*)q + (size_t)row * 512 + e0);
      qv[0] = qq[0]; qv[1] = qq[1]; qv[2] = qq[2]; qv[3] = qq[3];
    } else {
      uint2 uq = *(const uint2*)((const bf16*)q + (size_t)row * 512 + e0);
      qv[0] = bflo(uq.x); qv[1] = bfhi(uq.x); qv[2] = bflo(uq.y); qv[3] = bfhi(uq.y);
    }
    x[0] = qv[0] + bflo(um.x) + bflo(ua.x);
    x[1] = qv[1] + bfhi(um.x) + bfhi(ua.x);
    x[2] = qv[2] + bflo(um.y) + bflo(ua.y);
    x[3] = qv[3] + bfhi(um.y) + bfhi(ua.y);
  }
  float s = x[0] + x[1] + x[2] + x[3];
  float s2 = x[0] * x[0] + x[1] * x[1] + x[2] * x[2] + x[3] * x[3];
  #pragma unroll
  for (int off = 1; off <= 16; off <<= 1) {
    s  += __shfl_xor(s, off, 64);
    s2 += __shfl_xor(s2, off, 64);
  }
  float m = s * (1.0f / 128.0f);
  float rinv = rsqrtf(s2 * (1.0f / 128.0f) - m * m + 1e-5f);
  f32x4 ga = *(const f32x4*)(gamF + e0);
  f32x4 be = *(const f32x4*)(gamF + 512 + e0);
  float y[4];
  #pragma unroll
  for (int j = 0; j < 4; ++j) y[j] = (x[j] - m) * rinv * ga[j] + be[j];
  if (f32) {
    f32x4 ov = {y[0], y[1], y[2], y[3]};
    *(f32x4*)((float*)out + (size_t)row * 512 + e0) = ov;
  } else {
    bf16 ov[4] = {(bf16)y[0], (bf16)y[1], (bf16)y[2], (bf16)y[3]};
    *(uint2*)((bf16*)out + (size_t)row * 512 + e0) = *(const uint2*)ov;
  }
}

// ---------- launch ----------
extern "C" void kernel_launch(void* const* d_in, const int* in_sizes, int n_in,
                              void* d_out, int out_size, void* d_ws, size_t ws_size,
                              hipStream_t stream) {
  (void)in_sizes; (void)n_in; (void)out_size; (void)ws_size;
  const void* q      = d_in[0];
  const void* spike  = d_in[1];
  const void* mask   = d_in[2];
  const void* tl     = d_in[3];
  const void* w_prim = d_in[4];
  const void* b_prim = d_in[5];
  const void* anchors= d_in[6];
  const void* lsig   = d_in[7];
  const void* w_aggr = d_in[8];
  const void* b_aggr = d_in[9];
  const void* w_q    = d_in[10];
  const void* b_q    = d_in[11];
  const void* w_k    = d_in[12];
  const void* b_k    = d_in[13];
  const void* w_v    = d_in[14];
  const void* b_v    = d_in[15];
  const void* w_o    = d_in[16];
  const void* b_o    = d_in[17];
  const void* gam    = d_in[18];
  const void* bet    = d_in[19];

  char* ws = (char*)d_ws;
  bf16*  Wall   = (bf16*)(ws + 0);            // 3,145,728
  bf16*  q_rot  = (bf16*)(ws + 3145728);      // 8,388,608
  float* qn     = (float*)(ws + 11534336);    // 4,194,304
  bf16*  MQ     = (bf16*)(ws + 15728640);     // 16,777,216
  float* h_part = (float*)(ws + 32505856);    // 4,194,304
  float* pd_part= (float*)(ws + 36700160);    // 8,192
  float* Kh     = (float*)(ws + 36708352);    // 262,144
  float* Vh     = (float*)(ws + 36970496);    // 262,144
  bf16*  attn_o = (bf16*)(ws + 37232640);     // 8,388,608
  bf16*  msg_a  = (bf16*)(ws + 45621248);     // 8,388,608
  float* biasF  = (float*)(ws + 54009856);    // 16,384 (end 54,026,240)

  prologue<<<5640, 256, 0, stream>>>(w_prim, w_q, w_o, w_aggr, w_k, w_v,
                                     b_prim, b_q, b_o, b_aggr, b_k, b_v, gam, bet,
                                     q, spike, tl, mask, Wall, biasF, q_rot, qn);
  gemm_dist<<<640, 256, 0, stream>>>(q_rot, Wall, biasF + 0, biasF + 512, MQ,
                                     qn, anchors, lsig, mask, h_part, pd_part);
  qlin_akv<<<dim3(128, 2), 256, 0, stream>>>(h_part, pd_part,
                                             Wall + 3 * 262144, biasF + 1536,
                                             Wall + 4 * 262144, biasF + 2048,
                                             Wall + 5 * 262144, biasF + 2560, Kh, Vh);
  attn_v3<<<512, 256, 0, stream>>>(MQ, Kh, Vh, attn_o);
  gemm2<<<dim3(64, 8), 256, 0, stream>>>(attn_o, Wall + 2 * 262144, biasF + 1024, msg_a);
  ln_v2<<<4096, 256, 0, stream>>>(q, mask, MQ, msg_a, biasF + 3072, d_out);
}

// Round 11
// 210.165 us; speedup vs baseline: 1.1610x; 1.1082x over previous
//
#include <hip/hip_runtime.h>
#include <hip/hip_bf16.h>

typedef __hip_bfloat16 bf16;
typedef __attribute__((ext_vector_type(8))) short bf16x8;
typedef __attribute__((ext_vector_type(4))) float f32x4;

// ---------- helpers ----------
__device__ __forceinline__ float bflo(unsigned u) { return __uint_as_float(u << 16); }
__device__ __forceinline__ float bfhi(unsigned u) { return __uint_as_float(u & 0xffff0000u); }
__device__ __forceinline__ bool probe_f32(const void* mask) {
  return *(const unsigned*)mask == 0x3F800000u;
}
__device__ __forceinline__ float ldin(const void* p, size_t i, bool f32) {
  return f32 ? ((const float*)p)[i] : (float)((const bf16*)p)[i];
}

// ---------- 1. prologue: pack_w + prep biases + spike rotation ----------
__global__ __launch_bounds__(256) void prologue(
    const void* w0, const void* w1, const void* w2, const void* w3,
    const void* w4, const void* w5,
    const void* b0, const void* b1, const void* b2, const void* b3,
    const void* b4, const void* b5, const void* g, const void* be,
    const void* q, const void* spike, const void* theta_logit, const void* mask,
    bf16* __restrict__ Wall, float* __restrict__ biasF,
    bf16* __restrict__ q_rot, float* __restrict__ qn) {
  bool f32 = probe_f32(mask);
  int blk = blockIdx.x, t = threadIdx.x;
  if (blk < 1536) {
    const int compT[4][4] = {{0,1,2,3},{1,0,3,2},{2,3,0,1},{3,2,1,0}};
    const float signT[4][4] = {{1.f,-1.f,-1.f,-1.f},{1.f,1.f,-1.f,1.f},{1.f,1.f,1.f,-1.f},{1.f,-1.f,1.f,1.f}};
    int E = blk * 1024 + t * 4;
    int wi = E >> 18;
    const void* src = wi == 0 ? w0 : wi == 1 ? w1 : wi == 2 ? w2 : wi == 3 ? w3 : wi == 4 ? w4 : w5;
    bf16 ov[4];
    #pragma unroll
    for (int j = 0; j < 4; ++j) {
      int e = (E + j) & 262143;
      int o = e >> 9, kk = e & 511;
      int ro = o >> 7, a = o & 127, co = kk >> 7, b2 = kk & 127;
      ov[j] = (bf16)(ldin(src, compT[ro][co] * 16384 + a * 128 + b2, f32) * signT[ro][co]);
    }
    *(uint2*)(Wall + E) = *(const uint2*)ov;
  } else if (blk < 1544) {
    int b = blk - 1536;
    const void* src = b == 0 ? b0 : b == 1 ? b1 : b == 2 ? b2 : b == 3 ? b3
                    : b == 4 ? b4 : b == 5 ? b5 : b == 6 ? g : be;
    biasF[b * 512 + t] = ldin(src, t, f32);
    biasF[b * 512 + 256 + t] = ldin(src, 256 + t, f32);
  } else {
    int row = (blk - 1544) * 2 + (t >> 7);
    int l = t & 127;
    float tl = ldin(theta_logit, 0, f32);
    float tmax = 1.5707963267948966f / (1.0f + __expf(-tl));
    float th = tmax * ldin(spike, row, f32);
    float c = cosf(th), s = sinf(th);
    size_t base = (size_t)row * 512;
    float a = ldin(q, base + l, f32), b = ldin(q, base + 128 + l, f32);
    float cc = ldin(q, base + 256 + l, f32), d = ldin(q, base + 384 + l, f32);
    float r0 = c * a - s * d;
    float r1 = c * b - s * cc;
    float r2 = c * cc + s * b;
    float r3 = c * d + s * a;
    bf16* orow = q_rot + base;
    orow[l] = (bf16)r0; orow[128 + l] = (bf16)r1; orow[256 + l] = (bf16)r2; orow[384 + l] = (bf16)r3;
    qn[(size_t)row * 128 + l] = r0 * r0 + r1 * r1 + r2 * r2 + r3 * r3;
  }
}

// ---------- shared staging: B-tile [64 rows x 512 k] -> fragment-major LDS ----------
__device__ __forceinline__ void stage_B64(const bf16* __restrict__ Bw, int n0, char* Bs, int t) {
  int r = t & 63, cb = (t >> 6) * 16;
  const bf16* src = Bw + (size_t)(n0 + r) * 512;
  #pragma unroll
  for (int i = 0; i < 16; ++i) {
    int c = cb + i;
    int off = (c >> 2) * 4096 + (r >> 4) * 1024 + (((c & 3) * 16 + (r & 15)) * 16);
    *(uint4*)(Bs + off) = *(const uint4*)(src + c * 8);
  }
}

// ---------- 2. FUSED dist_h + gemm1 (dist FIRST so it rides the first residency wave) ----------
// blocks [0,128): dist_h (b=blk>>4, nc=blk&15)
// blocks [128,640): gemm1 tile; g=blk-128, m0=(g&31)*256, n0=(g>>5)*64
//   -> blk%8 == (g%8) == m-tile%8: all 16 n-tiles of one A-slab land on one XCD (L2-local A)
__global__ __launch_bounds__(256, 2) void gemm_dist(
    const bf16* __restrict__ A, const bf16* __restrict__ Bw,
    const float* __restrict__ bias0, const float* __restrict__ bias1,
    bf16* __restrict__ MQ,
    const float* __restrict__ qn, const void* anchors, const void* lsig,
    const void* mask, float* __restrict__ h_part, float* __restrict__ pd_part) {
  __shared__ char smem[77952];
  const int t = threadIdx.x;
  if (blockIdx.x >= 128) {
    char* Bs = smem;
    const int g = blockIdx.x - 128;
    const int wave = t >> 6, lane = t & 63;
    const int quad = lane >> 4, l16 = lane & 15;
    const int m0 = (g & 31) * 256, n0 = (g >> 5) * 64;
    stage_B64(Bw, n0, Bs, t);
    __syncthreads();
    const int mbase = m0 + wave * 64;
    f32x4 acc[4][4] = {};
    bf16x8 areg[2][4], breg[2][4];
    #pragma unroll
    for (int mt = 0; mt < 4; ++mt)
      areg[0][mt] = *(const bf16x8*)(A + (size_t)(mbase + mt * 16 + l16) * 512 + quad * 8);
    #pragma unroll
    for (int nt = 0; nt < 4; ++nt)
      breg[0][nt] = *(const bf16x8*)(Bs + nt * 1024 + lane * 16);
    #pragma unroll
    for (int kk = 0; kk < 16; ++kk) {
      const int cur = kk & 1, nxt = cur ^ 1;
      if (kk < 15) {
        const int k2 = (kk + 1) * 32;
        #pragma unroll
        for (int mt = 0; mt < 4; ++mt)
          areg[nxt][mt] = *(const bf16x8*)(A + (size_t)(mbase + mt * 16 + l16) * 512 + k2 + quad * 8);
        #pragma unroll
        for (int nt = 0; nt < 4; ++nt)
          breg[nxt][nt] = *(const bf16x8*)(Bs + (kk + 1) * 4096 + nt * 1024 + lane * 16);
      }
      #pragma unroll
      for (int mt = 0; mt < 4; ++mt)
        #pragma unroll
        for (int nt = 0; nt < 4; ++nt)
          acc[mt][nt] = __builtin_amdgcn_mfma_f32_16x16x32_bf16(areg[cur][mt], breg[cur][nt],
                                                                acc[mt][nt], 0, 0, 0);
    }
    #pragma unroll
    for (int nt = 0; nt < 4; ++nt) {
      int col = n0 + nt * 16 + l16;
      float bv = col < 512 ? bias0[col] : bias1[col - 512];
      #pragma unroll
      for (int mt = 0; mt < 4; ++mt) {
        int rb = mbase + mt * 16 + quad * 4;
        #pragma unroll
        for (int r = 0; r < 4; ++r)
          MQ[(size_t)(rb + r) * 1024 + col] = (bf16)(acc[mt][nt][r] + bv);
      }
    }
  } else {
    bool f32 = probe_f32(mask);
    bf16*  qr   = (bf16*)smem;                  // 65536 B
    float* an   = (float*)(smem + 65536);       // 8192 B
    float* sInc = (float*)(smem + 73728);       // 4096 B
    float* rs   = (float*)(smem + 77824);       // 64 B
    float* pd   = (float*)(smem + 77888);       // 64 B
    int bb = blockIdx.x;
    int b = bb >> 4, nc = bb & 15;
    {
      const uint4* src = (const uint4*)((const bf16*)A + ((size_t)b * 1024 + nc * 64) * 512);
      uint4* dst = (uint4*)qr;
      #pragma unroll
      for (int i = 0; i < 8; ++i) dst[t + i * 256] = src[t + i * 256];
    }
    for (int i = t; i < 2048; i += 256) {
      int k = i >> 7, l = i & 127;
      float a0 = ldin(anchors, k * 512 + l, f32);
      float a1 = ldin(anchors, k * 512 + 128 + l, f32);
      float a2 = ldin(anchors, k * 512 + 256 + l, f32);
      float a3 = ldin(anchors, k * 512 + 384 + l, f32);
      an[i] = a0 * a0 + a1 * a1 + a2 * a2 + a3 * a3;
    }
    if (t < 16) {
      float ls = ldin(lsig, t, f32);
      float ssq = __expf(ls); ssq = fmaxf(ssq * ssq, 1e-6f);
      rs[t] = -1.0f / ssq;
      pd[t] = 0.0f;
    }
    __syncthreads();
    {
      int rl = t >> 2, part = t & 3;
      int n = nc * 64 + rl;
      const float* qrow = qn + ((size_t)b * 1024 + n) * 128 + part * 32;
      f32x4 q4[8];
      #pragma unroll
      for (int i = 0; i < 8; ++i) q4[i] = *(const f32x4*)(qrow + i * 4);
      float sc[16] = {};
      #pragma unroll
      for (int i = 0; i < 8; ++i) {
        #pragma unroll
        for (int k = 0; k < 16; ++k) {
          f32x4 av = *(const f32x4*)(an + k * 128 + part * 32 + i * 4);
          sc[k] += q4[i][0] * av[0] + q4[i][1] * av[1] + q4[i][2] * av[2] + q4[i][3] * av[3];
        }
      }
      #pragma unroll
      for (int k = 0; k < 16; ++k) {
        sc[k] += __shfl_xor(sc[k], 1, 64);
        sc[k] += __shfl_xor(sc[k], 2, 64);
      }
      if (part == 0) {
        float mval = ldin(mask, b * 1024 + n, f32);
        #pragma unroll
        for (int k = 0; k < 16; ++k) {
          float inc = __expf(sc[k] * rs[k]) * mval;
          sInc[k * 64 + rl] = inc;
          atomicAdd(&pd[k], inc);
        }
      }
    }
    __syncthreads();
    {
      float acc0[16] = {}, acc1[16] = {};
      for (int nn = 0; nn < 64; ++nn) {
        float v0 = (float)qr[nn * 512 + t];
        float v1 = (float)qr[nn * 512 + 256 + t];
        #pragma unroll
        for (int k = 0; k < 16; ++k) {
          float p = sInc[k * 64 + nn];
          acc0[k] += p * v0;
          acc1[k] += p * v1;
        }
      }
      #pragma unroll
      for (int k = 0; k < 16; ++k) {
        size_t base = ((size_t)(b * 16 + k) * 16 + nc) * 512;
        h_part[base + t] = acc0[k];
        h_part[base + 256 + t] = acc1[k];
      }
    }
    if (t < 16) pd_part[((size_t)(b * 16 + t)) * 16 + nc] = pd[t];
  }
}

// ---------- 3. GEMM2: msg_a = attn_o @ Wo^T + b_o, grid 64x8 (id%8 = m%8: A L2-local) ----------
__global__ __launch_bounds__(256, 2) void gemm2(
    const bf16* __restrict__ A, const bf16* __restrict__ Bw,
    const float* __restrict__ biasO, bf16* __restrict__ msg_a) {
  __shared__ char Bs[65536];
  const int t = threadIdx.x;
  const int wave = t >> 6, lane = t & 63;
  const int quad = lane >> 4, l16 = lane & 15;
  const int m0 = blockIdx.x * 128, n0 = blockIdx.y * 64;
  stage_B64(Bw, n0, Bs, t);
  __syncthreads();
  const int mbase = m0 + wave * 32;
  f32x4 acc[2][4] = {};
  bf16x8 areg[2][2], breg[2][4];
  #pragma unroll
  for (int mt = 0; mt < 2; ++mt)
    areg[0][mt] = *(const bf16x8*)(A + (size_t)(mbase + mt * 16 + l16) * 512 + quad * 8);
  #pragma unroll
  for (int nt = 0; nt < 4; ++nt)
    breg[0][nt] = *(const bf16x8*)(Bs + nt * 1024 + lane * 16);
  #pragma unroll
  for (int kk = 0; kk < 16; ++kk) {
    const int cur = kk & 1, nxt = cur ^ 1;
    if (kk < 15) {
      const int k2 = (kk + 1) * 32;
      #pragma unroll
      for (int mt = 0; mt < 2; ++mt)
        areg[nxt][mt] = *(const bf16x8*)(A + (size_t)(mbase + mt * 16 + l16) * 512 + k2 + quad * 8);
      #pragma unroll
      for (int nt = 0; nt < 4; ++nt)
        breg[nxt][nt] = *(const bf16x8*)(Bs + (kk + 1) * 4096 + nt * 1024 + lane * 16);
    }
    #pragma unroll
    for (int mt = 0; mt < 2; ++mt)
      #pragma unroll
      for (int nt = 0; nt < 4; ++nt)
        acc[mt][nt] = __builtin_amdgcn_mfma_f32_16x16x32_bf16(areg[cur][mt], breg[cur][nt],
                                                              acc[mt][nt], 0, 0, 0);
  }
  #pragma unroll
  for (int nt = 0; nt < 4; ++nt) {
    int col = n0 + nt * 16 + l16;
    float bv = biasO[col];
    #pragma unroll
    for (int mt = 0; mt < 2; ++mt) {
      int rb = mbase + mt * 16 + quad * 4;
      #pragma unroll
      for (int r = 0; r < 4; ++r)
        msg_a[(size_t)(rb + r) * 512 + col] = (bf16)(acc[mt][nt][r] + bv);
    }
  }
}

// ---------- 4. fused reduce + aggr(full, redundant) + K/V(half): grid (128,2) x 256 ----------
__global__ __launch_bounds__(256) void qlin_akv(
    const float* __restrict__ h_part, const float* __restrict__ pd_part,
    const bf16* __restrict__ Wa, const float* __restrict__ ba,
    const bf16* __restrict__ Wk, const float* __restrict__ bk,
    const bf16* __restrict__ Wv, const float* __restrict__ bv,
    float* __restrict__ Kh, float* __restrict__ Vh) {
  __shared__ float xs[512];
  __shared__ float ys[512];
  int row = blockIdx.x, half = blockIdx.y;
  int t = threadIdx.x;            // 256
  float dsum = 0.0f;
  #pragma unroll
  for (int nc = 0; nc < 16; ++nc) dsum += pd_part[row * 16 + nc];
  float dinv = 1.0f / fmaxf(dsum, 1e-6f);
  #pragma unroll
  for (int j = 0; j < 2; ++j) {
    int d = j * 256 + t;
    float hv = 0.0f;
    #pragma unroll
    for (int nc = 0; nc < 16; ++nc) hv += h_part[(size_t)row * 8192 + nc * 512 + d];
    xs[d] = hv * dinv;
  }
  __syncthreads();
  #pragma unroll
  for (int j = 0; j < 2; ++j) {
    int o = j * 256 + t;
    const uint4* wr = (const uint4*)(Wa + (size_t)o * 512);
    float acc = ba[o];
    #pragma unroll 4
    for (int c = 0; c < 64; ++c) {
      uint4 u = wr[c];
      const float* xp = xs + c * 8;
      acc += xp[0] * bflo(u.x) + xp[1] * bfhi(u.x)
           + xp[2] * bflo(u.y) + xp[3] * bfhi(u.y)
           + xp[4] * bflo(u.z) + xp[5] * bfhi(u.z)
           + xp[6] * bflo(u.w) + xp[7] * bfhi(u.w);
    }
    ys[o] = acc;
  }
  __syncthreads();
  {
    int o = half * 256 + t;
    const uint4* wk = (const uint4*)(Wk + (size_t)o * 512);
    const uint4* wv = (const uint4*)(Wv + (size_t)o * 512);
    float ak = bk[o], av = bv[o];
    #pragma unroll 2
    for (int c = 0; c < 64; ++c) {
      uint4 uk = wk[c], uv = wv[c];
      const float* xp = ys + c * 8;
      ak += xp[0] * bflo(uk.x) + xp[1] * bfhi(uk.x)
          + xp[2] * bflo(uk.y) + xp[3] * bfhi(uk.y)
          + xp[4] * bflo(uk.z) + xp[5] * bfhi(uk.z)
          + xp[6] * bflo(uk.w) + xp[7] * bfhi(uk.w);
      av += xp[0] * bflo(uv.x) + xp[1] * bfhi(uv.x)
          + xp[2] * bflo(uv.y) + xp[3] * bfhi(uv.y)
          + xp[4] * bflo(uv.z) + xp[5] * bfhi(uv.z)
          + xp[6] * bflo(uv.w) + xp[7] * bfhi(uv.w);
    }
    Kh[(size_t)row * 512 + o] = ak;
    Vh[(size_t)row * 512 + o] = av;
  }
}

// ---------- 5. attention: 16 rows/block, grid 512 ----------
__global__ __launch_bounds__(256) void attn_v3(
    const bf16* __restrict__ MQ, const float* __restrict__ Kh_g,
    const float* __restrict__ Vh_g, bf16* __restrict__ attn_o) {
  __shared__ float KV[8 * 1092];
  __shared__ float P[16 * 132];
  const int t = threadIdx.x;         // 256
  const int rowbase = blockIdx.x * 16;
  const int b = rowbase >> 10;
  for (int i = t; i < 8192; i += 256) {
    int k = i >> 9, d = i & 511, h = d >> 6, dd = d & 63;
    KV[h * 1092 + k * 68 + dd] = Kh_g[(size_t)b * 8192 + i];
  }
  __syncthreads();
  {
    const int r = t >> 4, h = (t >> 1) & 7, hf = t & 1;
    const int grow = rowbase + r;
    const uint4* qp = (const uint4*)(MQ + (size_t)grow * 1024 + 512 + h * 64 + hf * 32);
    float q[32];
    #pragma unroll
    for (int i = 0; i < 4; ++i) {
      uint4 u = qp[i];
      q[i * 8 + 0] = bflo(u.x); q[i * 8 + 1] = bfhi(u.x);
      q[i * 8 + 2] = bflo(u.y); q[i * 8 + 3] = bfhi(u.y);
      q[i * 8 + 4] = bflo(u.z); q[i * 8 + 5] = bfhi(u.z);
      q[i * 8 + 6] = bflo(u.w); q[i * 8 + 7] = bfhi(u.w);
    }
    float sc[16];
    #pragma unroll
    for (int k = 0; k < 16; ++k) {
      float s = 0.0f;
      #pragma unroll
      for (int d4 = 0; d4 < 8; ++d4) {
        f32x4 kv = *(const f32x4*)(KV + h * 1092 + k * 68 + hf * 32 + d4 * 4);
        s += q[d4 * 4 + 0] * kv[0] + q[d4 * 4 + 1] * kv[1]
           + q[d4 * 4 + 2] * kv[2] + q[d4 * 4 + 3] * kv[3];
      }
      sc[k] = s;
    }
    #pragma unroll
    for (int k = 0; k < 16; ++k) sc[k] += __shfl_xor(sc[k], 1, 64);
    if (hf == 0) {
      #pragma unroll
      for (int k = 0; k < 16; ++k) sc[k] *= 0.125f;
      float m = sc[0];
      #pragma unroll
      for (int k = 1; k < 16; ++k) m = fmaxf(m, sc[k]);
      float ssum = 0.0f;
      #pragma unroll
      for (int k = 0; k < 16; ++k) { sc[k] = __expf(sc[k] - m); ssum += sc[k]; }
      float inv = 1.0f / ssum;
      #pragma unroll
      for (int k = 0; k < 16; ++k) P[r * 132 + h * 16 + k] = sc[k] * inv;
    }
  }
  __syncthreads();
  for (int i = t; i < 8192; i += 256) {
    int k = i >> 9, d = i & 511, h = d >> 6, dd = d & 63;
    KV[h * 1092 + k * 68 + dd] = Vh_g[(size_t)b * 8192 + i];
  }
  __syncthreads();
  {
    const int r = t >> 4, dg = t & 15;
    #pragma unroll
    for (int h = 0; h < 8; ++h) {
      float a0 = 0, a1 = 0, a2 = 0, a3 = 0;
      #pragma unroll
      for (int k = 0; k < 16; ++k) {
        float p = P[r * 132 + h * 16 + k];
        f32x4 va = *(const f32x4*)(KV + h * 1092 + k * 68 + dg * 4);
        a0 += p * va[0]; a1 += p * va[1]; a2 += p * va[2]; a3 += p * va[3];
      }
      bf16 ov[4] = {(bf16)a0, (bf16)a1, (bf16)a2, (bf16)a3};
      *(uint2*)(attn_o + (size_t)(rowbase + r) * 512 + h * 64 + dg * 4) = *(const uint2*)ov;
    }
  }
}

// ---------- 6. residual + per-component LayerNorm ----------
__global__ __launch_bounds__(256) void ln_v2(
    const void* q, const void* mask, const bf16* __restrict__ MQ,
    const bf16* __restrict__ msg_a, const float* __restrict__ gamF, void* out) {
  bool f32 = probe_f32(mask);
  int t = threadIdx.x;
  int row = blockIdx.x * 2 + (t >> 7);
  int l = t & 127;
  int e0 = l * 4;
  float x[4];
  {
    uint2 um = *(const uint2*)(MQ + (size_t)row * 1024 + e0);
    uint2 ua = *(const uint2*)(msg_a + (size_t)row * 512 + e0);
    float qv[4];
    if (f32) {
      f32x4 qq = *(const f32x4*)((const float*)q + (size_t)row * 512 + e0);
      qv[0] = qq[0]; qv[1] = qq[1]; qv[2] = qq[2]; qv[3] = qq[3];
    } else {
      uint2 uq = *(const uint2*)((const bf16*)q + (size_t)row * 512 + e0);
      qv[0] = bflo(uq.x); qv[1] = bfhi(uq.x); qv[2] = bflo(uq.y); qv[3] = bfhi(uq.y);
    }
    x[0] = qv[0] + bflo(um.x) + bflo(ua.x);
    x[1] = qv[1] + bfhi(um.x) + bfhi(ua.x);
    x[2] = qv[2] + bflo(um.y) + bflo(ua.y);
    x[3] = qv[3] + bfhi(um.y) + bfhi(ua.y);
  }
  float s = x[0] + x[1] + x[2] + x[3];
  float s2 = x[0] * x[0] + x[1] * x[1] + x[2] * x[2] + x[3] * x[3];
  #pragma unroll
  for (int off = 1; off <= 16; off <<= 1) {
    s  += __shfl_xor(s, off, 64);
    s2 += __shfl_xor(s2, off, 64);
  }
  float m = s * (1.0f / 128.0f);
  float rinv = rsqrtf(s2 * (1.0f / 128.0f) - m * m + 1e-5f);
  f32x4 ga = *(const f32x4*)(gamF + e0);
  f32x4 be = *(const f32x4*)(gamF + 512 + e0);
  float y[4];
  #pragma unroll
  for (int j = 0; j < 4; ++j) y[j] = (x[j] - m) * rinv * ga[j] + be[j];
  if (f32) {
    f32x4 ov = {y[0], y[1], y[2], y[3]};
    *(f32x4*)((float*)out + (size_t)row * 512 + e0) = ov;
  } else {
    bf16 ov[4] = {(bf16)y[0], (bf16)y[1], (bf16)y[2], (bf16)y[3]};
    *(uint2*)((bf16*)out + (size_t)row * 512 + e0) = *(const uint2*)ov;
  }
}

// ---------- launch ----------
extern "C" void kernel_launch(void* const* d_in, const int* in_sizes, int n_in,
                              void* d_out, int out_size, void* d_ws, size_t ws_size,
                              hipStream_t stream) {
  (void)in_sizes; (void)n_in; (void)out_size; (void)ws_size;
  const void* q      = d_in[0];
  const void* spike  = d_in[1];
  const void* mask   = d_in[2];
  const void* tl     = d_in[3];
  const void* w_prim = d_in[4];
  const void* b_prim = d_in[5];
  const void* anchors= d_in[6];
  const void* lsig   = d_in[7];
  const void* w_aggr = d_in[8];
  const void* b_aggr = d_in[9];
  const void* w_q    = d_in[10];
  const void* b_q    = d_in[11];
  const void* w_k    = d_in[12];
  const void* b_k    = d_in[13];
  const void* w_v    = d_in[14];
  const void* b_v    = d_in[15];
  const void* w_o    = d_in[16];
  const void* b_o    = d_in[17];
  const void* gam    = d_in[18];
  const void* bet    = d_in[19];

  char* ws = (char*)d_ws;
  bf16*  Wall   = (bf16*)(ws + 0);            // 3,145,728
  bf16*  q_rot  = (bf16*)(ws + 3145728);      // 8,388,608
  float* qn     = (float*)(ws + 11534336);    // 4,194,304
  bf16*  MQ     = (bf16*)(ws + 15728640);     // 16,777,216
  float* h_part = (float*)(ws + 32505856);    // 4,194,304
  float* pd_part= (float*)(ws + 36700160);    // 8,192
  float* Kh     = (float*)(ws + 36708352);    // 262,144
  float* Vh     = (float*)(ws + 36970496);    // 262,144
  bf16*  attn_o = (bf16*)(ws + 37232640);     // 8,388,608
  bf16*  msg_a  = (bf16*)(ws + 45621248);     // 8,388,608
  float* biasF  = (float*)(ws + 54009856);    // 16,384 (end 54,026,240)

  prologue<<<5640, 256, 0, stream>>>(w_prim, w_q, w_o, w_aggr, w_k, w_v,
                                     b_prim, b_q, b_o, b_aggr, b_k, b_v, gam, bet,
                                     q, spike, tl, mask, Wall, biasF, q_rot, qn);
  gemm_dist<<<640, 256, 0, stream>>>(q_rot, Wall, biasF + 0, biasF + 512, MQ,
                                     qn, anchors, lsig, mask, h_part, pd_part);
  qlin_akv<<<dim3(128, 2), 256, 0, stream>>>(h_part, pd_part,
                                             Wall + 3 * 262144, biasF + 1536,
                                             Wall + 4 * 262144, biasF + 2048,
                                             Wall + 5 * 262144, biasF + 2560, Kh, Vh);
  attn_v3<<<512, 256, 0, stream>>>(MQ, Kh, Vh, attn_o);
  gemm2<<<dim3(64, 8), 256, 0, stream>>>(attn_o, Wall + 2 * 262144, biasF + 1024, msg_a);
  ln_v2<<<4096, 256, 0, stream>>>(q, mask, MQ, msg_a, biasF + 3072, d_out);
}